// Round 16
// baseline (165.357 us; speedup 1.0000x reference)
//
#include <hip/hip_runtime.h>
#include <math.h>

// ---------------- problem constants ----------------
#define MM 2048             // B*N keypoints
#define HOImg 512
#define GG 1024             // HG*WG
#define NCTRL 64
#define NPAR 132            // NPARAM*2

#define BN_S 0.9999950000374997f   // 1/sqrt(1+1e-5)

typedef __bf16 bf16x8 __attribute__((ext_vector_type(8)));
typedef float  f32x4  __attribute__((ext_vector_type(4)));

__device__ __forceinline__ unsigned short f2b(float v){
    unsigned u = __float_as_uint(v);
    unsigned r = (u + 0x7FFFu + ((u>>16)&1u)) >> 16;
    return (unsigned short)r;
}
__device__ __forceinline__ float b2f(unsigned short s){
    return __uint_as_float(((unsigned)s)<<16);
}

// async global->LDS, 16B per lane, LDS dest = uniform base + lane*16
__device__ __forceinline__ void gload_lds16(const void* g, void* l){
    __builtin_amdgcn_global_load_lds((const __attribute__((address_space(1))) void*)g,
                                     (__attribute__((address_space(3))) void*)l, 16, 0, 0);
}

// ===== prep_xb: x (4,64,128,128) f32 -> xp bf16 [4][130][130][96] =====
__global__ __launch_bounds__(256) void prep_xb_k(const float* __restrict__ x,
    short* __restrict__ XH)
{
    __shared__ float sT[64][65];
    const int xt = blockIdx.x, yo = blockIdx.y, b = blockIdx.z;
    const int tid = threadIdx.x;
    const int x0 = xt*64;

    if (yo == 0 || yo == 129){
        for (int e = tid; e < 6240; e += 256){
            int idx = xt*6240 + e;
            size_t o = (((size_t)b*130 + yo)*130 + idx/96)*96 + idx%96;
            XH[o] = 0;
        }
        return;
    }
    const int ys = yo - 1;
    for (int e = tid; e < 64*64; e += 256) {
        int ci = e >> 6, xl = e & 63;
        sT[ci][xl] = x[(((size_t)b*64 + ci)*128 + ys)*128 + x0 + xl];
    }
    if (tid < 96){
        size_t o = (((size_t)b*130 + yo)*130 + (xt?129:0))*96 + tid;
        XH[o] = 0;
    }
    __syncthreads();
    const float gy = -1.f + ys*(2.f/127.f);
    for (int e = tid; e < 64*96; e += 256) {
        int xl = e / 96, ci = e - xl*96;
        int xs = x0 + xl;
        float v;
        if (ci < 64) v = sT[ci][xl];
        else if (ci == 64) v = -1.f + xs*(2.f/127.f);
        else if (ci == 65) v = gy;
        else v = 0.f;
        size_t o = (((size_t)b*130 + yo)*130 + (xs+1))*96 + ci;
        XH[o] = (short)f2b(v);
    }
}

// ===== prep_misc: w1 prep (0..127), w2 prep (128..255), zero_h (256..767)
__global__ __launch_bounds__(256) void prep_misc_k(const float* __restrict__ w1,
    const float* __restrict__ w2, short* __restrict__ B1H,
    short* __restrict__ B2H, short* __restrict__ HH)
{
    int bid = blockIdx.x;
    if (bid < 128){
        int co = bid;
        for (int e = threadIdx.x; e < 864; e += 256){
            int kp = e / 96, ci = e - kp*96;
            float v = 0.f;
            if (ci < 66){ int ky = kp/3, kx = kp - (kp/3)*3; v = w1[((co*66 + ci)*3 + ky)*3 + kx]; }
            B1H[co*864+e] = (short)f2b(v);
        }
    } else if (bid < 256){
        int co = bid - 128;
        for (int e = threadIdx.x; e < 1152; e += 256){
            int kp = e >> 7, ci = e & 127;
            int ky = kp/3, kx = kp - (kp/3)*3;
            float v = w2[((co*128 + ci)*3 + ky)*3 + kx];
            B2H[co*1152+e] = (short)f2b(v);
        }
    } else {
        int t = (bid-256)*256 + threadIdx.x;
        if (t < 131072){
            int b = t >> 15; int r = t & 32767;
            int ci = r & 127; int col = (r>>7)&1; int y = r>>8;
            size_t o = (((size_t)b*128 + y)*130 + 128+col)*128 + ci;
            HH[o] = 0;
        }
    }
}

// ===== MFMA implicit-GEMM 3x3 conv, plain bf16, FULL-CHUNK B register preload ==
// launch_bounds(256,1): lift the 128-VGPR cap (R9/R5's prefetch attempts were
// silently squeezed out by (256,4)/(256,2) caps). Bc[9][4] = 144 VGPRs of B
// issued right after the chunk barrier; per-kp chain shrinks to LDS-A -> MFMA.
// Per-output accumulation order over (cc,kp) identical -> bit-identical output.
template<int CCH, int HR, int HO_, int WO_, bool SPLIT>
__global__ __launch_bounds__(256, 1) void convm_k(
    const short* __restrict__ IN, const short* __restrict__ Bm,
    short* __restrict__ Oh, float* __restrict__ Of)
{
    constexpr int WR = 130;
    constexpr int KTOT = 9*CCH;
    constexpr int NC = CCH/32;
    __shared__ __align__(16) short sA[2][8448];    // 2 bufs x 1056 int4
    const int tid = threadIdx.x;
    const int x0 = blockIdx.x*64;
    const int y0 = blockIdx.y*2;
    const int b  = blockIdx.z;
    const int wv = tid>>6, lane = tid&63;
    const int wm = wv>>1, wn = wv&1;
    const int l15 = lane&15, lg = lane>>4;

    f32x4 acc[4][4];
    #pragma unroll
    for(int i=0;i<4;i++)
        #pragma unroll
        for(int j=0;j<4;j++) acc[i][j] = (f32x4)(0.0f);

    const int vofs = (wn*64 + l15)*KTOT + lg*8;

    auto stage = [&](int buf, int cc){
        const size_t inH = (((size_t)b*HR + y0)*WR + x0)*CCH + (size_t)cc*32;
        #pragma unroll
        for (int j=0;j<5;j++){
            int s = wv*264 + j*64 + lane;          // int4 slot 0..1055
            int q = s >> 2;
            int r = q/66, xx = q - r*66;
            int cb = (s & 3) ^ (xx & 3);           // inverse swizzle on source
            const short* src = IN + inH + ((size_t)r*WR + xx)*CCH + cb*8;
            short* dst = &sA[buf][(wv*264 + j*64)*8];
            if (j < 4 || lane < 8) gload_lds16(src, dst);
        }
    };
    auto loadA = [&](bf16x8* dA, const short* sAc, int kp){
        const int ky = kp/3, kx = kp - (kp/3)*3;
        const int r = wm + ky;
        #pragma unroll
        for (int mt=0; mt<4; ++mt){
            int xx = mt*16 + l15 + kx;
            int slot = (r*66+xx)*4 + (lg ^ (xx&3));
            dA[mt] = *(const bf16x8*)&sAc[slot*8];
        }
    };

    stage(0, 0);
    if (NC > 1) stage(1, 1);

    for (int cc = 0; cc < NC; ++cc){
        if (cc+1 < NC) { asm volatile("s_waitcnt vmcnt(5)" ::: "memory"); }
        else           { asm volatile("s_waitcnt vmcnt(0)" ::: "memory"); }
        __builtin_amdgcn_s_barrier();
        const short* sAc = &sA[cc&1][0];

        // preload this chunk's ENTIRE B slice (36 x bf16x8 = 144 VGPR).
        // Loads issue back-to-back here; early kp-steps' MFMAs cover the
        // latency of the later Bc entries (in-order vmcnt retirement).
        bf16x8 Bc[9][4];
        #pragma unroll
        for (int kp=0;kp<9;kp++){
            const int ko = kp*CCH + cc*32;
            #pragma unroll
            for (int nt=0;nt<4;nt++)
                Bc[kp][nt] = *(const bf16x8*)(Bm + vofs + nt*(16*KTOT) + ko);
        }

        #pragma unroll
        for (int kp=0;kp<9;kp++){
            bf16x8 A[4];
            loadA(A, sAc, kp);
            #pragma unroll
            for (int mt=0;mt<4;mt++)
                #pragma unroll
                for (int nt=0;nt<4;nt++)
                    acc[mt][nt] = __builtin_amdgcn_mfma_f32_16x16x32_bf16(A[mt], Bc[kp][nt], acc[mt][nt],0,0,0);
        }
        asm volatile("s_waitcnt lgkmcnt(0)" ::: "memory");
        __builtin_amdgcn_s_barrier();
        if (cc+2 < NC) stage(cc&1, cc+2);
    }

    const int y = y0 + wm;
    #pragma unroll
    for (int mt=0;mt<4;mt++){
        #pragma unroll
        for (int reg=0;reg<4;reg++){
            const int xo = x0 + mt*16 + lg*4 + reg;
            if (WO_ == 128 || xo < WO_){
                #pragma unroll
                for (int nt=0;nt<4;nt++){
                    const int co = wn*64 + nt*16 + l15;
                    float v = fmaxf(acc[mt][nt][reg]*BN_S, 0.f);
                    if (SPLIT){
                        size_t o = (((size_t)b*HO_ + y)*WR + xo)*128 + co;
                        Oh[o] = (short)f2b(v);
                    } else {
                        size_t o = (((size_t)b*HO_ + y)*(size_t)WO_ + xo)*128 + co;
                        Of[o] = v;
                    }
                }
            }
        }
    }
}

// ===== constants: shuffle-based reduce (1 block, 1024 thr) =====
__global__ __launch_bounds__(1024) void consts_red_k(float* __restrict__ cbuf,
    float* __restrict__ pgn, float* __restrict__ ctrl)
{
    __shared__ float part[16][4];
    __shared__ float res[4];
    int g = threadIdx.x;
    int i = g >> 5, j = g & 31;
    float xs = (j + 0.5f)*(2.0f/32.0f) - 1.0f;
    float ys = (i + 0.5f)*(2.0f/32.0f) - 1.0f;
    float norm = (xs + 1.0f)*0.5f;
    float r_ = 1.0f + norm*31.0f;
    float r_s = (r_ - 1.0f)/31.0f*2.0f*32.0f/512.0f;
    float t_s = (ys + 1.0f)*3.14159265358979323846f;
    float bx = r_s*cosf(t_s);
    float by = r_s*sinf(t_s);

    float mnx=bx, mxx=bx, mny=by, mxy=by;
    #pragma unroll
    for (int s=1; s<64; s<<=1){
        mnx = fminf(mnx, __shfl_xor(mnx, s));
        mxx = fmaxf(mxx, __shfl_xor(mxx, s));
        mny = fminf(mny, __shfl_xor(mny, s));
        mxy = fmaxf(mxy, __shfl_xor(mxy, s));
    }
    int wv = g>>6, ln = g&63;
    if (ln == 0){ part[wv][0]=mnx; part[wv][1]=mxx; part[wv][2]=mny; part[wv][3]=mxy; }
    __syncthreads();
    if (g < 4){
        float v = part[0][g];
        for (int t=1;t<16;t++) v = (g&1) ? fmaxf(v, part[t][g]) : fminf(v, part[t][g]);
        res[g] = v;
    }
    __syncthreads();
    float minx=res[0], maxx=res[1], miny=res[2], maxy=res[3];
    float ptpx = maxx-minx, ptpy = maxy-miny;
    if (g == 0){ cbuf[0]=minx; cbuf[1]=miny; cbuf[2]=ptpx; cbuf[3]=ptpy; }

    float pgx = (bx - minx)/(ptpx + 1e-8f)*0.3f + 0.35f;
    float pgy = (by - miny)/(ptpy + 1e-8f)*0.3f + 0.35f;
    pgn[2*g]   = pgx;
    pgn[2*g+1] = pgy;
    if ((i&3)==0 && (j&3)==0){ int t = (i>>2)*8 + (j>>2); ctrl[t*2]=pgx; ctrl[t*2+1]=pgy; }
}

// ===== Ug fill: bf16 U+ matrix [1024 g][96 k] =====
__global__ __launch_bounds__(256) void ug_fill_k(const float* __restrict__ pgn,
    const float* __restrict__ ctrl, unsigned short* __restrict__ Ug)
{
    __shared__ float sc[64][2];
    int g = blockIdx.x*256 + threadIdx.x;
    for (int e = threadIdx.x; e < 128; e += 256) sc[e>>1][e&1] = ctrl[e];
    __syncthreads();
    float px = pgn[2*g], py = pgn[2*g+1];
    float gg2 = px*px + py*py;
    unsigned int* dst = (unsigned int*)(Ug + (size_t)g*96);
    #pragma unroll
    for (int t=0;t<64;t+=2){
        float cx0=sc[t][0],   cy0=sc[t][1];
        float cx1=sc[t+1][0], cy1=sc[t+1][1];
        float r20 = fmaxf(gg2 + (cx0*cx0+cy0*cy0) - 2.f*(px*cx0+py*cy0), 0.f);
        float r21 = fmaxf(gg2 + (cx1*cx1+cy1*cy1) - 2.f*(px*cx1+py*cy1), 0.f);
        float u0 = r20*logf(sqrtf(r20+1e-12f)+1e-6f);
        float u1 = r21*logf(sqrtf(r21+1e-12f)+1e-6f);
        dst[t>>1] = (unsigned)f2b(u0) | ((unsigned)f2b(u1)<<16);
    }
    dst[32] = (unsigned)f2b(1.f) | ((unsigned)f2b(px)<<16);
    dst[33] = (unsigned)f2b(py);               // hi half = 0
    #pragma unroll
    for (int t=34;t<48;t++) dst[t] = 0u;
}

// ===== fused MLP+TPS: interp -> lin1 -> lin2 -> lin3 -> tps GEMM =====
__global__ __launch_bounds__(256) void mlp_tps_k(const float* __restrict__ Theta,
    const int* __restrict__ kp,
    const float* __restrict__ l1w, const float* __restrict__ l1b,
    const float* __restrict__ l2w, const float* __restrict__ l2b,
    const float* __restrict__ l3w, const float* __restrict__ l3b,
    const unsigned short* __restrict__ Ug, float* __restrict__ bxy)
{
    __shared__ float th0[8][128];
    __shared__ float th1[8][256];
    __shared__ float th2[8][256];
    __shared__ float sth[8][132];
    __shared__ __align__(16) unsigned short sW[16][96];
    const int m0 = blockIdx.x*8;
    const int tid = threadIdx.x;

    // ---- interp (th0) ----
    #pragma unroll
    for (int it=0; it<4; ++it){
        int e = tid + it*256;
        int kpi = e >> 7, c = e & 127;
        int m = m0 + kpi;
        int b = m >> 9;
        float ix = (float)kp[m*2+0]/511.f*125.f;
        float iy = (float)kp[m*2+1]/511.f*125.f;
        float x0 = floorf(ix), y0 = floorf(iy);
        float wx = ix-x0, wy = iy-y0;
        const float* f = Theta + (size_t)b*126*126*128 + c;
        float r = 0.f;
        #pragma unroll
        for (int t=0;t<4;t++){
            float xi = x0 + (t&1), yi = y0 + (t>>1);
            float wt = ((t&1)?wx:(1.f-wx)) * ((t>>1)?wy:(1.f-wy));
            bool v = (xi>=0.f)&&(xi<=125.f)&&(yi>=0.f)&&(yi<=125.f);
            int xc=(int)fminf(fmaxf(xi,0.f),125.f), yc=(int)fminf(fmaxf(yi,0.f),125.f);
            r += f[((size_t)yc*126 + xc)*128]*(v?wt:0.f);
        }
        th0[kpi][c] = r;
    }
    __syncthreads();
    // ---- lin1 ----
    {
        int o = tid;
        float acc[8] = {0,0,0,0,0,0,0,0};
        const float* wr = l1w + o*128;
        for (int i=0;i<128;i++){
            float wv = wr[i];
            #pragma unroll
            for (int j=0;j<8;j++) acc[j] += th0[j][i]*wv;
        }
        float bv = l1b[o];
        #pragma unroll
        for (int j=0;j<8;j++) th1[j][o] = fmaxf((acc[j]+bv)*BN_S, 0.f);
    }
    __syncthreads();
    // ---- lin2 ----
    {
        int o = tid;
        float acc[8] = {0,0,0,0,0,0,0,0};
        const float* wr = l2w + o*256;
        for (int i=0;i<256;i++){
            float wv = wr[i];
            #pragma unroll
            for (int j=0;j<8;j++) acc[j] += th1[j][i]*wv;
        }
        float bv = l2b[o];
        #pragma unroll
        for (int j=0;j<8;j++) th2[j][o] = fmaxf(acc[j]+bv, 0.f);
    }
    __syncthreads();
    // ---- lin3 (tanh -> theta) ----
    if (tid < NPAR){
        int o = tid;
        float acc[8] = {0,0,0,0,0,0,0,0};
        const float* wr = l3w + o*256;
        for (int i=0;i<256;i++){
            float wv = wr[i];
            #pragma unroll
            for (int j=0;j<8;j++) acc[j] += th2[j][i]*wv;
        }
        float bv = l3b[o];
        #pragma unroll
        for (int j=0;j<8;j++) sth[j][o] = tanhf(acc[j]+bv);
    }
    __syncthreads();
    // ---- W+ prep ----
    if (tid < 16){
        int kpi = tid>>1, c = tid&1;
        float s = 0.f;
        for (int p=0;p<63;p++){ float w = sth[kpi][2*p+c]; s += w; sW[tid][1+p] = f2b(w); }
        sW[tid][0]  = f2b(-s);
        sW[tid][64] = f2b(sth[kpi][126+c]);
        sW[tid][65] = f2b(sth[kpi][128+c]);
        sW[tid][66] = f2b(sth[kpi][130+c]);
        for (int p=67;p<96;p++) sW[tid][p] = 0;
    }
    __syncthreads();
    // ---- TPS MFMA: bxy = Ug(1024x96) @ W+(96x16cols) ----
    const int wv = tid>>6, lane = tid&63;
    const int l15 = lane&15, lg = lane>>4;
    bf16x8 Bf[3];
    #pragma unroll
    for (int ks=0;ks<3;ks++) Bf[ks] = *(const bf16x8*)&sW[l15][ks*32 + lg*8];
    const int gbase = wv*256;
    const int kpg = m0 + (l15>>1), c = l15&1;
    #pragma unroll
    for (int mf=0; mf<16; ++mf){
        f32x4 acc2 = (f32x4)(0.f);
        const unsigned short* ap = Ug + (size_t)(gbase + mf*16 + l15)*96 + lg*8;
        #pragma unroll
        for (int ks=0;ks<3;ks++){
            bf16x8 Af = *(const bf16x8*)(ap + ks*32);
            acc2 = __builtin_amdgcn_mfma_f32_16x16x32_bf16(Af, Bf[ks], acc2,0,0,0);
        }
        float* dst = bxy + ((size_t)kpg*2 + c)*1024 + gbase + mf*16 + lg*4;
        #pragma unroll
        for (int r=0;r<4;r++) dst[r] = acc2[r];
    }
}

// ===== sample: pure gather, one (keypoint, channel) per block ==============
__global__ __launch_bounds__(256) void sample3_k(const int* __restrict__ kp,
    const float* __restrict__ bxy, const float* __restrict__ pgn,
    const float* __restrict__ cbuf, const float* __restrict__ imgs,
    float* __restrict__ out)
{
    const int bid = blockIdx.x;
    const int m = ((bid & 7) << 8) | (bid >> 3);   // bijective: 2048 = 8*256
    const int ch = blockIdx.y;
    const int tid = threadIdx.x;
    const int b = m >> 9;
    const float vminx = cbuf[0] + ((float)kp[m*2+0]/512.f*2.f - 1.f);
    const float vminy = cbuf[1] + ((float)kp[m*2+1]/512.f*2.f - 1.f);
    const float ptpx = cbuf[2], ptpy = cbuf[3];
    const int g0 = tid*4;
    f32x4 zbx = *(const f32x4*)&bxy[((size_t)m*2+0)*1024 + g0];
    f32x4 zby = *(const f32x4*)&bxy[((size_t)m*2+1)*1024 + g0];
    f32x4 pga = *(const f32x4*)&pgn[2*g0];
    f32x4 pgb = *(const f32x4*)&pgn[2*g0+4];
    float px[4] = {pga[0], pga[2], pgb[0], pgb[2]};
    float py[4] = {pga[1], pga[3], pgb[1], pgb[3]};
    const float* ic = imgs + ((size_t)b*3 + ch)*HOImg*HOImg;
    f32x4 o;
    #pragma unroll
    for (int i=0;i<4;i++){
        float wnx = px[i] + zbx[i];
        float wny = py[i] + zby[i];
        float wxr = (wnx - 0.35f)/0.3f*ptpx + vminx;
        float wyr = (wny - 0.35f)/0.3f*ptpy + vminy;
        float ix = ((wxr + 1.f)*512.f - 1.f)*0.5f;
        float iy = ((wyr + 1.f)*512.f - 1.f)*0.5f;
        float x0f = floorf(ix), y0f = floorf(iy);
        float fx = ix-x0f, fy = iy-y0f;
        float w00=(1.f-fx)*(1.f-fy), w10=fx*(1.f-fy), w01=(1.f-fx)*fy, w11=fx*fy;
        bool vx0 = (x0f>=0.f)&&(x0f<=511.f), vx1 = (x0f+1.f>=0.f)&&(x0f+1.f<=511.f);
        bool vy0 = (y0f>=0.f)&&(y0f<=511.f), vy1 = (y0f+1.f>=0.f)&&(y0f+1.f<=511.f);
        float m00 = (vx0&&vy0)?w00:0.f;
        float m10 = (vx1&&vy0)?w10:0.f;
        float m01 = (vx0&&vy1)?w01:0.f;
        float m11 = (vx1&&vy1)?w11:0.f;
        int X0 = (int)fminf(fmaxf(x0f,0.f),511.f);
        int X1 = (int)fminf(fmaxf(x0f+1.f,0.f),511.f);
        int Y0 = (int)fminf(fmaxf(y0f,0.f),511.f);
        int Y1 = (int)fminf(fmaxf(y0f+1.f,0.f),511.f);
        int i00 = Y0*HOImg+X0, i10 = Y0*HOImg+X1, i01 = Y1*HOImg+X0, i11 = Y1*HOImg+X1;
        o[i] = ic[i00]*m00 + ic[i10]*m10 + ic[i01]*m01 + ic[i11]*m11;
    }
    *(f32x4*)&out[((size_t)(m*3+ch))*GG + g0] = o;
}

// ============================ launcher =======================================
extern "C" void kernel_launch(void* const* d_in, const int* in_sizes, int n_in,
                              void* d_out, int out_size, void* d_ws, size_t ws_size,
                              hipStream_t stream)
{
    const float* x    = (const float*)d_in[0];
    const float* imgs = (const float*)d_in[1];
    const int*   kp   = (const int*)d_in[2];
    const float* c1w  = (const float*)d_in[3];
    const float* c2w  = (const float*)d_in[4];
    const float* l1w  = (const float*)d_in[5];
    const float* l1b  = (const float*)d_in[6];
    const float* l2w  = (const float*)d_in[7];
    const float* l2b  = (const float*)d_in[8];
    const float* l3w  = (const float*)d_in[9];
    const float* l3b  = (const float*)d_in[10];
    float* out = (float*)d_out;

    // ---- workspace layout (alias-audited; identical to R13/R15 passing runs) --
    // [0, 32.51MB)   xph (dead after conv1) / Theta (written by conv2)
    // [32.51, 49.55) hh (conv1 out; dead after conv2)
    // [49.55, 50.07) B1, B2 (live whole run)
    // [50.07, 67.05) Ug, pgn, cbuf, ctrl, bxy — dedicated, never aliased
    char* W = (char*)d_ws;
    short* xph   = (short*)(W + 0);
    float* Theta = (float*)(W + 0);
    constexpr size_t OFF_HH = 32514048;
    short* hh   = (short*)(W + OFF_HH);
    constexpr size_t OFF_B = OFF_HH + 17039360;        // 49,553,408
    short* B1 = (short*)(W + OFF_B);
    short* B2 = (short*)(W + OFF_B + 221184);
    constexpr size_t OFF_C = OFF_B + 516096;           // 50,069,504
    unsigned short* Ug = (unsigned short*)(W + OFF_C);
    float* pgn  = (float*)(W + OFF_C + 196608);
    float* cbuf = (float*)(W + OFF_C + 204800);
    float* ctrl = (float*)(W + OFF_C + 205056);
    float* bxy  = (float*)(W + OFF_C + 205568);

    hipLaunchKernelGGL(prep_xb_k, dim3(2,130,4), dim3(256), 0, stream, x, xph);
    hipLaunchKernelGGL(prep_misc_k, dim3(768), dim3(256), 0, stream,
                       c1w, c2w, B1, B2, hh);
    hipLaunchKernelGGL(consts_red_k, dim3(1), dim3(1024), 0, stream, cbuf, pgn, ctrl);
    hipLaunchKernelGGL(ug_fill_k, dim3(4), dim3(256), 0, stream, pgn, ctrl, Ug);

    hipLaunchKernelGGL((convm_k<96,130,128,128,true>), dim3(2,64,4), dim3(256), 0, stream,
                       xph, B1, hh, (float*)nullptr);
    hipLaunchKernelGGL((convm_k<128,128,126,126,false>), dim3(2,63,4), dim3(256), 0, stream,
                       hh, B2, (short*)nullptr, Theta);

    hipLaunchKernelGGL(mlp_tps_k, dim3(MM/8), dim3(256), 0, stream,
                       Theta, kp, l1w, l1b, l2w, l2b, l3w, l3b, Ug, bxy);
    hipLaunchKernelGGL(sample3_k, dim3(MM, 3), dim3(256), 0, stream,
                       kp, bxy, pgn, cbuf, imgs, out);
}

// Round 17
// 161.290 us; speedup vs baseline: 1.0252x; 1.0252x over previous
//
#include <hip/hip_runtime.h>
#include <math.h>

// ---------------- problem constants ----------------
#define MM 2048             // B*N keypoints
#define HOImg 512
#define GG 1024             // HG*WG
#define NCTRL 64
#define NPAR 132            // NPARAM*2

#define BN_S 0.9999950000374997f   // 1/sqrt(1+1e-5)

typedef __bf16 bf16x8 __attribute__((ext_vector_type(8)));
typedef float  f32x4  __attribute__((ext_vector_type(4)));

__device__ __forceinline__ unsigned short f2b(float v){
    unsigned u = __float_as_uint(v);
    unsigned r = (u + 0x7FFFu + ((u>>16)&1u)) >> 16;
    return (unsigned short)r;
}
__device__ __forceinline__ float b2f(unsigned short s){
    return __uint_as_float(((unsigned)s)<<16);
}

// async global->LDS, 16B per lane, LDS dest = uniform base + lane*16
__device__ __forceinline__ void gload_lds16(const void* g, void* l){
    __builtin_amdgcn_global_load_lds((const __attribute__((address_space(1))) void*)g,
                                     (__attribute__((address_space(3))) void*)l, 16, 0, 0);
}

// ===== prep_xb: x (4,64,128,128) f32 -> xp bf16 [4][130][130][64] =====
// (coord channels removed — handled analytically in conv1's epilogue)
__global__ __launch_bounds__(256) void prep_xb_k(const float* __restrict__ x,
    short* __restrict__ XH)
{
    __shared__ float sT[64][65];
    const int xt = blockIdx.x, yo = blockIdx.y, b = blockIdx.z;
    const int tid = threadIdx.x;
    const int x0 = xt*64;

    if (yo == 0 || yo == 129){
        for (int e = tid; e < 4160; e += 256){      // half of 130*64
            int idx = xt*4160 + e;
            size_t o = (((size_t)b*130 + yo)*130 + idx/64)*64 + (idx&63);
            XH[o] = 0;
        }
        return;
    }
    const int ys = yo - 1;
    for (int e = tid; e < 64*64; e += 256) {
        int ci = e >> 6, xl = e & 63;
        sT[ci][xl] = x[(((size_t)b*64 + ci)*128 + ys)*128 + x0 + xl];
    }
    if (tid < 64){
        size_t o = (((size_t)b*130 + yo)*130 + (xt?129:0))*64 + tid;
        XH[o] = 0;
    }
    __syncthreads();
    for (int e = tid; e < 64*64; e += 256) {
        int xl = e >> 6, ci = e & 63;
        size_t o = (((size_t)b*130 + yo)*130 + (x0+xl+1))*64 + ci;
        XH[o] = (short)f2b(sT[ci][xl]);
    }
}

// ===== prep_misc: B1 (0..127), B2 (128..255), zero_h (256..767), tab (768..772)
// tab[(py*3+px)*128+co][3] = {A,B,C}: coord-channel contribution of conv1 as
// T = A + B*xo + C*y, per border-validity pattern (py,px) — exact f32.
__global__ __launch_bounds__(256) void prep_misc_k(const float* __restrict__ w1,
    const float* __restrict__ w2, short* __restrict__ B1H,
    short* __restrict__ B2H, short* __restrict__ HH, float* __restrict__ Tab)
{
    int bid = blockIdx.x;
    if (bid < 128){
        int co = bid;
        for (int e = threadIdx.x; e < 576; e += 256){
            int kp = e >> 6, ci = e & 63;
            int ky = kp/3, kx = kp - (kp/3)*3;
            float v = w1[((co*66 + ci)*3 + ky)*3 + kx];
            B1H[co*576+e] = (short)f2b(v);
        }
    } else if (bid < 256){
        int co = bid - 128;
        for (int e = threadIdx.x; e < 1152; e += 256){
            int kp = e >> 7, ci = e & 127;
            int ky = kp/3, kx = kp - (kp/3)*3;
            float v = w2[((co*128 + ci)*3 + ky)*3 + kx];
            B2H[co*1152+e] = (short)f2b(v);
        }
    } else if (bid < 768){
        int t = (bid-256)*256 + threadIdx.x;
        if (t < 131072){
            int b = t >> 15; int r = t & 32767;
            int ci = r & 127; int col = (r>>7)&1; int y = r>>8;
            size_t o = (((size_t)b*128 + y)*130 + 128+col)*128 + ci;
            HH[o] = 0;
        }
    } else {
        int i = (bid-768)*256 + threadIdx.x;
        if (i < 1152){
            int co = i/9, comb = i - (i/9)*9;
            int py = comb/3, px = comb - py*3;
            float w64[3][3], w65[3][3];
            #pragma unroll
            for (int ky=0;ky<3;ky++)
                #pragma unroll
                for (int kx=0;kx<3;kx++){
                    w64[ky][kx] = w1[((co*66 + 64)*3 + ky)*3 + kx];
                    w65[ky][kx] = w1[((co*66 + 65)*3 + ky)*3 + kx];
                }
            const int ky0 = (py==0)?1:0, ky1 = (py==2)?1:2;
            const int kx0 = (px==0)?1:0, kx1 = (px==2)?1:2;
            const float s = 2.f/127.f;
            float A = 0.f, Bc = 0.f, Cc = 0.f;
            for (int kx=kx0; kx<=kx1; ++kx){
                float wy = 0.f;
                for (int ky=ky0; ky<=ky1; ++ky) wy += w64[ky][kx];
                A  += wy * (-1.f + (float)(kx-1)*s);
                Bc += wy * s;
            }
            for (int ky=ky0; ky<=ky1; ++ky){
                float wx = 0.f;
                for (int kx=kx0; kx<=kx1; ++kx) wx += w65[ky][kx];
                A  += wx * (-1.f + (float)(ky-1)*s);
                Cc += wx * s;
            }
            float* d = Tab + ((size_t)comb*128 + co)*3;
            d[0] = A; d[1] = Bc; d[2] = Cc;
        }
    }
}

// ===== MFMA implicit-GEMM 3x3 conv, plain bf16, 64col x 2row x 128co block ====
// COORD: conv1 — K covers only the 64 real channels; coord-channel term added
// in the epilogue from Tab (exact f32 affine per border pattern).
template<int CCH, int HR, int HO_, int WO_, bool SPLIT, bool COORD>
__global__ __launch_bounds__(256, 2) void convm_k(
    const short* __restrict__ IN, const short* __restrict__ Bm,
    const float* __restrict__ Tab,
    short* __restrict__ Oh, float* __restrict__ Of)
{
    constexpr int WR = 130;
    constexpr int KTOT = 9*CCH;
    constexpr int NC = CCH/32;
    __shared__ __align__(16) short sA[2][8448];    // 2 bufs x 1056 int4
    const int tid = threadIdx.x;
    const int x0 = blockIdx.x*64;
    const int y0 = blockIdx.y*2;
    const int b  = blockIdx.z;
    const int wv = tid>>6, lane = tid&63;
    const int wm = wv>>1, wn = wv&1;
    const int l15 = lane&15, lg = lane>>4;

    f32x4 acc[4][4];
    #pragma unroll
    for(int i=0;i<4;i++)
        #pragma unroll
        for(int j=0;j<4;j++) acc[i][j] = (f32x4)(0.0f);

    const int vofs = (wn*64 + l15)*KTOT + lg*8;

    auto stage = [&](int buf, int cc){
        const size_t inH = (((size_t)b*HR + y0)*WR + x0)*CCH + (size_t)cc*32;
        #pragma unroll
        for (int j=0;j<5;j++){
            int s = wv*264 + j*64 + lane;          // int4 slot 0..1055
            int q = s >> 2;
            int r = q/66, xx = q - r*66;
            int cb = (s & 3) ^ (xx & 3);           // inverse swizzle on source
            const short* src = IN + inH + ((size_t)r*WR + xx)*CCH + cb*8;
            short* dst = &sA[buf][(wv*264 + j*64)*8];
            if (j < 4 || lane < 8) gload_lds16(src, dst);
        }
    };
    auto loadA = [&](bf16x8* dA, const short* sAc, int kp){
        const int ky = kp/3, kx = kp - (kp/3)*3;
        const int r = wm + ky;
        #pragma unroll
        for (int mt=0; mt<4; ++mt){
            int xx = mt*16 + l15 + kx;
            int slot = (r*66+xx)*4 + (lg ^ (xx&3));
            dA[mt] = *(const bf16x8*)&sAc[slot*8];
        }
    };

    stage(0, 0);
    if (NC > 1) stage(1, 1);

    for (int cc = 0; cc < NC; ++cc){
        if (cc+1 < NC) { asm volatile("s_waitcnt vmcnt(5)" ::: "memory"); }
        else           { asm volatile("s_waitcnt vmcnt(0)" ::: "memory"); }
        __builtin_amdgcn_s_barrier();
        const short* sAc = &sA[cc&1][0];
        #pragma unroll
        for (int kp=0;kp<9;kp++){
            bf16x8 A[4], Bv[4];
            loadA(A, sAc, kp);
            const int ko = kp*CCH + cc*32;
            #pragma unroll
            for (int nt=0;nt<4;nt++)
                Bv[nt] = *(const bf16x8*)(Bm + vofs + nt*(16*KTOT) + ko);
            #pragma unroll
            for (int mt=0;mt<4;mt++)
                #pragma unroll
                for (int nt=0;nt<4;nt++)
                    acc[mt][nt] = __builtin_amdgcn_mfma_f32_16x16x32_bf16(A[mt], Bv[nt], acc[mt][nt],0,0,0);
        }
        asm volatile("s_waitcnt lgkmcnt(0)" ::: "memory");
        __builtin_amdgcn_s_barrier();
        if (cc+2 < NC) stage(cc&1, cc+2);
    }

    const int y = y0 + wm;
    const int py = COORD ? ((y==0)?0:((y==127)?2:1)) : 0;
    #pragma unroll
    for (int mt=0;mt<4;mt++){
        #pragma unroll
        for (int reg=0;reg<4;reg++){
            const int xo = x0 + mt*16 + lg*4 + reg;
            if (WO_ == 128 || xo < WO_){
                const int px = COORD ? ((xo==0)?0:((xo==127)?2:1)) : 0;
                #pragma unroll
                for (int nt=0;nt<4;nt++){
                    const int co = wn*64 + nt*16 + l15;
                    float a = acc[mt][nt][reg];
                    if (COORD){
                        const float* t3 = Tab + ((size_t)(py*3+px)*128 + co)*3;
                        a += t3[0] + t3[1]*(float)xo + t3[2]*(float)y;
                    }
                    float v = fmaxf(a*BN_S, 0.f);
                    if (SPLIT){
                        size_t o = (((size_t)b*HO_ + y)*WR + xo)*128 + co;
                        Oh[o] = (short)f2b(v);
                    } else {
                        size_t o = (((size_t)b*HO_ + y)*(size_t)WO_ + xo)*128 + co;
                        Of[o] = v;
                    }
                }
            }
        }
    }
}

// ===== constants: shuffle-based reduce (1 block, 1024 thr) =====
__global__ __launch_bounds__(1024) void consts_red_k(float* __restrict__ cbuf,
    float* __restrict__ pgn, float* __restrict__ ctrl)
{
    __shared__ float part[16][4];
    __shared__ float res[4];
    int g = threadIdx.x;
    int i = g >> 5, j = g & 31;
    float xs = (j + 0.5f)*(2.0f/32.0f) - 1.0f;
    float ys = (i + 0.5f)*(2.0f/32.0f) - 1.0f;
    float norm = (xs + 1.0f)*0.5f;
    float r_ = 1.0f + norm*31.0f;
    float r_s = (r_ - 1.0f)/31.0f*2.0f*32.0f/512.0f;
    float t_s = (ys + 1.0f)*3.14159265358979323846f;
    float bx = r_s*cosf(t_s);
    float by = r_s*sinf(t_s);

    float mnx=bx, mxx=bx, mny=by, mxy=by;
    #pragma unroll
    for (int s=1; s<64; s<<=1){
        mnx = fminf(mnx, __shfl_xor(mnx, s));
        mxx = fmaxf(mxx, __shfl_xor(mxx, s));
        mny = fminf(mny, __shfl_xor(mny, s));
        mxy = fmaxf(mxy, __shfl_xor(mxy, s));
    }
    int wv = g>>6, ln = g&63;
    if (ln == 0){ part[wv][0]=mnx; part[wv][1]=mxx; part[wv][2]=mny; part[wv][3]=mxy; }
    __syncthreads();
    if (g < 4){
        float v = part[0][g];
        for (int t=1;t<16;t++) v = (g&1) ? fmaxf(v, part[t][g]) : fminf(v, part[t][g]);
        res[g] = v;
    }
    __syncthreads();
    float minx=res[0], maxx=res[1], miny=res[2], maxy=res[3];
    float ptpx = maxx-minx, ptpy = maxy-miny;
    if (g == 0){ cbuf[0]=minx; cbuf[1]=miny; cbuf[2]=ptpx; cbuf[3]=ptpy; }

    float pgx = (bx - minx)/(ptpx + 1e-8f)*0.3f + 0.35f;
    float pgy = (by - miny)/(ptpy + 1e-8f)*0.3f + 0.35f;
    pgn[2*g]   = pgx;
    pgn[2*g+1] = pgy;
    if ((i&3)==0 && (j&3)==0){ int t = (i>>2)*8 + (j>>2); ctrl[t*2]=pgx; ctrl[t*2+1]=pgy; }
}

// ===== Ug fill: bf16 U+ matrix [1024 g][96 k] =====
__global__ __launch_bounds__(256) void ug_fill_k(const float* __restrict__ pgn,
    const float* __restrict__ ctrl, unsigned short* __restrict__ Ug)
{
    __shared__ float sc[64][2];
    int g = blockIdx.x*256 + threadIdx.x;
    for (int e = threadIdx.x; e < 128; e += 256) sc[e>>1][e&1] = ctrl[e];
    __syncthreads();
    float px = pgn[2*g], py = pgn[2*g+1];
    float gg2 = px*px + py*py;
    unsigned int* dst = (unsigned int*)(Ug + (size_t)g*96);
    #pragma unroll
    for (int t=0;t<64;t+=2){
        float cx0=sc[t][0],   cy0=sc[t][1];
        float cx1=sc[t+1][0], cy1=sc[t+1][1];
        float r20 = fmaxf(gg2 + (cx0*cx0+cy0*cy0) - 2.f*(px*cx0+py*cy0), 0.f);
        float r21 = fmaxf(gg2 + (cx1*cx1+cy1*cy1) - 2.f*(px*cx1+py*cy1), 0.f);
        float u0 = r20*logf(sqrtf(r20+1e-12f)+1e-6f);
        float u1 = r21*logf(sqrtf(r21+1e-12f)+1e-6f);
        dst[t>>1] = (unsigned)f2b(u0) | ((unsigned)f2b(u1)<<16);
    }
    dst[32] = (unsigned)f2b(1.f) | ((unsigned)f2b(px)<<16);
    dst[33] = (unsigned)f2b(py);               // hi half = 0
    #pragma unroll
    for (int t=34;t<48;t++) dst[t] = 0u;
}

// ===== fused MLP+TPS: interp -> lin1 -> lin2 -> lin3 -> tps GEMM =====
__global__ __launch_bounds__(256) void mlp_tps_k(const float* __restrict__ Theta,
    const int* __restrict__ kp,
    const float* __restrict__ l1w, const float* __restrict__ l1b,
    const float* __restrict__ l2w, const float* __restrict__ l2b,
    const float* __restrict__ l3w, const float* __restrict__ l3b,
    const unsigned short* __restrict__ Ug, float* __restrict__ bxy)
{
    __shared__ float th0[8][128];
    __shared__ float th1[8][256];
    __shared__ float th2[8][256];
    __shared__ float sth[8][132];
    __shared__ __align__(16) unsigned short sW[16][96];
    const int m0 = blockIdx.x*8;
    const int tid = threadIdx.x;

    // ---- interp (th0) ----
    #pragma unroll
    for (int it=0; it<4; ++it){
        int e = tid + it*256;
        int kpi = e >> 7, c = e & 127;
        int m = m0 + kpi;
        int b = m >> 9;
        float ix = (float)kp[m*2+0]/511.f*125.f;
        float iy = (float)kp[m*2+1]/511.f*125.f;
        float x0 = floorf(ix), y0 = floorf(iy);
        float wx = ix-x0, wy = iy-y0;
        const float* f = Theta + (size_t)b*126*126*128 + c;
        float r = 0.f;
        #pragma unroll
        for (int t=0;t<4;t++){
            float xi = x0 + (t&1), yi = y0 + (t>>1);
            float wt = ((t&1)?wx:(1.f-wx)) * ((t>>1)?wy:(1.f-wy));
            bool v = (xi>=0.f)&&(xi<=125.f)&&(yi>=0.f)&&(yi<=125.f);
            int xc=(int)fminf(fmaxf(xi,0.f),125.f), yc=(int)fminf(fmaxf(yi,0.f),125.f);
            r += f[((size_t)yc*126 + xc)*128]*(v?wt:0.f);
        }
        th0[kpi][c] = r;
    }
    __syncthreads();
    // ---- lin1 ----
    {
        int o = tid;
        float acc[8] = {0,0,0,0,0,0,0,0};
        const float* wr = l1w + o*128;
        for (int i=0;i<128;i++){
            float wv = wr[i];
            #pragma unroll
            for (int j=0;j<8;j++) acc[j] += th0[j][i]*wv;
        }
        float bv = l1b[o];
        #pragma unroll
        for (int j=0;j<8;j++) th1[j][o] = fmaxf((acc[j]+bv)*BN_S, 0.f);
    }
    __syncthreads();
    // ---- lin2 ----
    {
        int o = tid;
        float acc[8] = {0,0,0,0,0,0,0,0};
        const float* wr = l2w + o*256;
        for (int i=0;i<256;i++){
            float wv = wr[i];
            #pragma unroll
            for (int j=0;j<8;j++) acc[j] += th1[j][i]*wv;
        }
        float bv = l2b[o];
        #pragma unroll
        for (int j=0;j<8;j++) th2[j][o] = fmaxf(acc[j]+bv, 0.f);
    }
    __syncthreads();
    // ---- lin3 (tanh -> theta) ----
    if (tid < NPAR){
        int o = tid;
        float acc[8] = {0,0,0,0,0,0,0,0};
        const float* wr = l3w + o*256;
        for (int i=0;i<256;i++){
            float wv = wr[i];
            #pragma unroll
            for (int j=0;j<8;j++) acc[j] += th2[j][i]*wv;
        }
        float bv = l3b[o];
        #pragma unroll
        for (int j=0;j<8;j++) sth[j][o] = tanhf(acc[j]+bv);
    }
    __syncthreads();
    // ---- W+ prep ----
    if (tid < 16){
        int kpi = tid>>1, c = tid&1;
        float s = 0.f;
        for (int p=0;p<63;p++){ float w = sth[kpi][2*p+c]; s += w; sW[tid][1+p] = f2b(w); }
        sW[tid][0]  = f2b(-s);
        sW[tid][64] = f2b(sth[kpi][126+c]);
        sW[tid][65] = f2b(sth[kpi][128+c]);
        sW[tid][66] = f2b(sth[kpi][130+c]);
        for (int p=67;p<96;p++) sW[tid][p] = 0;
    }
    __syncthreads();
    // ---- TPS MFMA: bxy = Ug(1024x96) @ W+(96x16cols) ----
    const int wv = tid>>6, lane = tid&63;
    const int l15 = lane&15, lg = lane>>4;
    bf16x8 Bf[3];
    #pragma unroll
    for (int ks=0;ks<3;ks++) Bf[ks] = *(const bf16x8*)&sW[l15][ks*32 + lg*8];
    const int gbase = wv*256;
    const int kpg = m0 + (l15>>1), c = l15&1;
    #pragma unroll
    for (int mf=0; mf<16; ++mf){
        f32x4 acc2 = (f32x4)(0.f);
        const unsigned short* ap = Ug + (size_t)(gbase + mf*16 + l15)*96 + lg*8;
        #pragma unroll
        for (int ks=0;ks<3;ks++){
            bf16x8 Af = *(const bf16x8*)(ap + ks*32);
            acc2 = __builtin_amdgcn_mfma_f32_16x16x32_bf16(Af, Bf[ks], acc2,0,0,0);
        }
        float* dst = bxy + ((size_t)kpg*2 + c)*1024 + gbase + mf*16 + lg*4;
        #pragma unroll
        for (int r=0;r<4;r++) dst[r] = acc2[r];
    }
}

// ===== sample: pure gather, one (keypoint, channel) per block ==============
__global__ __launch_bounds__(256) void sample3_k(const int* __restrict__ kp,
    const float* __restrict__ bxy, const float* __restrict__ pgn,
    const float* __restrict__ cbuf, const float* __restrict__ imgs,
    float* __restrict__ out)
{
    const int bid = blockIdx.x;
    const int m = ((bid & 7) << 8) | (bid >> 3);   // bijective: 2048 = 8*256
    const int ch = blockIdx.y;
    const int tid = threadIdx.x;
    const int b = m >> 9;
    const float vminx = cbuf[0] + ((float)kp[m*2+0]/512.f*2.f - 1.f);
    const float vminy = cbuf[1] + ((float)kp[m*2+1]/512.f*2.f - 1.f);
    const float ptpx = cbuf[2], ptpy = cbuf[3];
    const int g0 = tid*4;
    f32x4 zbx = *(const f32x4*)&bxy[((size_t)m*2+0)*1024 + g0];
    f32x4 zby = *(const f32x4*)&bxy[((size_t)m*2+1)*1024 + g0];
    f32x4 pga = *(const f32x4*)&pgn[2*g0];
    f32x4 pgb = *(const f32x4*)&pgn[2*g0+4];
    float px[4] = {pga[0], pga[2], pgb[0], pgb[2]};
    float py[4] = {pga[1], pga[3], pgb[1], pgb[3]};
    const float* ic = imgs + ((size_t)b*3 + ch)*HOImg*HOImg;
    f32x4 o;
    #pragma unroll
    for (int i=0;i<4;i++){
        float wnx = px[i] + zbx[i];
        float wny = py[i] + zby[i];
        float wxr = (wnx - 0.35f)/0.3f*ptpx + vminx;
        float wyr = (wny - 0.35f)/0.3f*ptpy + vminy;
        float ix = ((wxr + 1.f)*512.f - 1.f)*0.5f;
        float iy = ((wyr + 1.f)*512.f - 1.f)*0.5f;
        float x0f = floorf(ix), y0f = floorf(iy);
        float fx = ix-x0f, fy = iy-y0f;
        float w00=(1.f-fx)*(1.f-fy), w10=fx*(1.f-fy), w01=(1.f-fx)*fy, w11=fx*fy;
        bool vx0 = (x0f>=0.f)&&(x0f<=511.f), vx1 = (x0f+1.f>=0.f)&&(x0f+1.f<=511.f);
        bool vy0 = (y0f>=0.f)&&(y0f<=511.f), vy1 = (y0f+1.f>=0.f)&&(y0f+1.f<=511.f);
        float m00 = (vx0&&vy0)?w00:0.f;
        float m10 = (vx1&&vy0)?w10:0.f;
        float m01 = (vx0&&vy1)?w01:0.f;
        float m11 = (vx1&&vy1)?w11:0.f;
        int X0 = (int)fminf(fmaxf(x0f,0.f),511.f);
        int X1 = (int)fminf(fmaxf(x0f+1.f,0.f),511.f);
        int Y0 = (int)fminf(fmaxf(y0f,0.f),511.f);
        int Y1 = (int)fminf(fmaxf(y0f+1.f,0.f),511.f);
        int i00 = Y0*HOImg+X0, i10 = Y0*HOImg+X1, i01 = Y1*HOImg+X0, i11 = Y1*HOImg+X1;
        o[i] = ic[i00]*m00 + ic[i10]*m10 + ic[i01]*m01 + ic[i11]*m11;
    }
    *(f32x4*)&out[((size_t)(m*3+ch))*GG + g0] = o;
}

// ============================ launcher =======================================
extern "C" void kernel_launch(void* const* d_in, const int* in_sizes, int n_in,
                              void* d_out, int out_size, void* d_ws, size_t ws_size,
                              hipStream_t stream)
{
    const float* x    = (const float*)d_in[0];
    const float* imgs = (const float*)d_in[1];
    const int*   kp   = (const int*)d_in[2];
    const float* c1w  = (const float*)d_in[3];
    const float* c2w  = (const float*)d_in[4];
    const float* l1w  = (const float*)d_in[5];
    const float* l1b  = (const float*)d_in[6];
    const float* l2w  = (const float*)d_in[7];
    const float* l2b  = (const float*)d_in[8];
    const float* l3w  = (const float*)d_in[9];
    const float* l3b  = (const float*)d_in[10];
    float* out = (float*)d_out;

    // ---- workspace layout (alias-audited) ----
    // [0, 32.51MB)   xph (bf16, 8.65MB, dead after conv1) / Theta (conv2 out)
    // [32.51, 49.55) hh (conv1 out; dead after conv2)
    // [49.55, 50.07) B1 (147KB), B2 (295KB) — live whole run
    // [50.07, 67.07) Ug, pgn, cbuf, ctrl, Tab, bxy — dedicated, never aliased
    char* W = (char*)d_ws;
    short* xph   = (short*)(W + 0);
    float* Theta = (float*)(W + 0);
    constexpr size_t OFF_HH = 32514048;
    short* hh   = (short*)(W + OFF_HH);
    constexpr size_t OFF_B = OFF_HH + 17039360;        // 49,553,408
    short* B1 = (short*)(W + OFF_B);                   // 128*576*2 = 147,456
    short* B2 = (short*)(W + OFF_B + 221184);          // 294,912
    constexpr size_t OFF_C = OFF_B + 516096;           // 50,069,504
    unsigned short* Ug = (unsigned short*)(W + OFF_C);          // 196,608
    float* pgn  = (float*)(W + OFF_C + 196608);                 // 8,192
    float* cbuf = (float*)(W + OFF_C + 204800);                 // 256
    float* ctrl = (float*)(W + OFF_C + 205056);                 // 512
    float* Tab  = (float*)(W + OFF_C + 205568);                 // 13,824
    float* bxy  = (float*)(W + OFF_C + 219392);                 // 16,777,216

    hipLaunchKernelGGL(prep_xb_k, dim3(2,130,4), dim3(256), 0, stream, x, xph);
    hipLaunchKernelGGL(prep_misc_k, dim3(773), dim3(256), 0, stream,
                       c1w, c2w, B1, B2, hh, Tab);
    hipLaunchKernelGGL(consts_red_k, dim3(1), dim3(1024), 0, stream, cbuf, pgn, ctrl);
    hipLaunchKernelGGL(ug_fill_k, dim3(4), dim3(256), 0, stream, pgn, ctrl, Ug);

    hipLaunchKernelGGL((convm_k<64,130,128,128,true,true>), dim3(2,64,4), dim3(256), 0, stream,
                       xph, B1, Tab, hh, (float*)nullptr);
    hipLaunchKernelGGL((convm_k<128,128,126,126,false,false>), dim3(2,63,4), dim3(256), 0, stream,
                       hh, B2, (const float*)nullptr, (short*)nullptr, Theta);

    hipLaunchKernelGGL(mlp_tps_k, dim3(MM/8), dim3(256), 0, stream,
                       Theta, kp, l1w, l1b, l2w, l2b, l3w, l3b, Ug, bxy);
    hipLaunchKernelGGL(sample3_k, dim3(MM, 3), dim3(256), 0, stream,
                       kp, bxy, pgn, cbuf, imgs, out);
}

// Round 19
// 121.500 us; speedup vs baseline: 1.3610x; 1.3275x over previous
//
#include <hip/hip_runtime.h>
#include <math.h>

// ---------------- problem constants ----------------
#define MM 2048             // B*N keypoints
#define HOImg 512
#define GG 1024             // HG*WG
#define NCTRL 64
#define NPAR 132            // NPARAM*2

#define BN_S 0.9999950000374997f   // 1/sqrt(1+1e-5)

typedef __bf16 bf16x8 __attribute__((ext_vector_type(8)));
typedef float  f32x4  __attribute__((ext_vector_type(4)));

__device__ __forceinline__ unsigned short f2b(float v){
    unsigned u = __float_as_uint(v);
    unsigned r = (u + 0x7FFFu + ((u>>16)&1u)) >> 16;
    return (unsigned short)r;
}
__device__ __forceinline__ float b2f(unsigned short s){
    return __uint_as_float(((unsigned)s)<<16);
}

// ===== prep_xb: x (4,64,128,128) f32 -> xp bf16 [4][130][130][64] =====
__global__ __launch_bounds__(256) void prep_xb_k(const float* __restrict__ x,
    short* __restrict__ XH)
{
    __shared__ float sT[64][65];
    const int xt = blockIdx.x, yo = blockIdx.y, b = blockIdx.z;
    const int tid = threadIdx.x;
    const int x0 = xt*64;

    if (yo == 0 || yo == 129){
        for (int e = tid; e < 4160; e += 256){      // half of 130*64
            int idx = xt*4160 + e;
            size_t o = (((size_t)b*130 + yo)*130 + idx/64)*64 + (idx&63);
            XH[o] = 0;
        }
        return;
    }
    const int ys = yo - 1;
    for (int e = tid; e < 64*64; e += 256) {
        int ci = e >> 6, xl = e & 63;
        sT[ci][xl] = x[(((size_t)b*64 + ci)*128 + ys)*128 + x0 + xl];
    }
    if (tid < 64){
        size_t o = (((size_t)b*130 + yo)*130 + (xt?129:0))*64 + tid;
        XH[o] = 0;
    }
    __syncthreads();
    for (int e = tid; e < 64*64; e += 256) {
        int xl = e >> 6, ci = e & 63;
        size_t o = (((size_t)b*130 + yo)*130 + (x0+xl+1))*64 + ci;
        XH[o] = (short)f2b(sT[ci][xl]);
    }
}

// ===== prep_misc: B1 (0..127), B2 (128..255), Tab (256..260) =====
__global__ __launch_bounds__(256) void prep_misc_k(const float* __restrict__ w1,
    const float* __restrict__ w2, short* __restrict__ B1H,
    short* __restrict__ B2H, float* __restrict__ Tab)
{
    int bid = blockIdx.x;
    if (bid < 128){
        int co = bid;
        for (int e = threadIdx.x; e < 576; e += 256){
            int kp = e >> 6, ci = e & 63;
            int ky = kp/3, kx = kp - (kp/3)*3;
            float v = w1[((co*66 + ci)*3 + ky)*3 + kx];
            B1H[co*576+e] = (short)f2b(v);
        }
    } else if (bid < 256){
        int co = bid - 128;
        for (int e = threadIdx.x; e < 1152; e += 256){
            int kp = e >> 7, ci = e & 127;
            int ky = kp/3, kx = kp - (kp/3)*3;
            float v = w2[((co*128 + ci)*3 + ky)*3 + kx];
            B2H[co*1152+e] = (short)f2b(v);
        }
    } else {
        int i = (bid-256)*256 + threadIdx.x;
        if (i < 1152){
            int co = i/9, comb = i - (i/9)*9;
            int py = comb/3, px = comb - py*3;
            float w64[3][3], w65[3][3];
            #pragma unroll
            for (int ky=0;ky<3;ky++)
                #pragma unroll
                for (int kx=0;kx<3;kx++){
                    w64[ky][kx] = w1[((co*66 + 64)*3 + ky)*3 + kx];
                    w65[ky][kx] = w1[((co*66 + 65)*3 + ky)*3 + kx];
                }
            const int ky0 = (py==0)?1:0, ky1 = (py==2)?1:2;
            const int kx0 = (px==0)?1:0, kx1 = (px==2)?1:2;
            const float s = 2.f/127.f;
            float A = 0.f, Bc = 0.f, Cc = 0.f;
            for (int kx=kx0; kx<=kx1; ++kx){
                float wy = 0.f;
                for (int ky=ky0; ky<=ky1; ++ky) wy += w64[ky][kx];
                A  += wy * (-1.f + (float)(kx-1)*s);
                Bc += wy * s;
            }
            for (int ky=ky0; ky<=ky1; ++ky){
                float wx = 0.f;
                for (int kx=kx0; kx<=kx1; ++kx) wx += w65[ky][kx];
                A  += wx * (-1.f + (float)(ky-1)*s);
                Cc += wx * s;
            }
            float* d = Tab + ((size_t)comb*128 + co)*3;
            d[0] = A; d[1] = Bc; d[2] = Cc;
        }
    }
}

// ===== SPARSE conv1+conv2+interp: one block = 4 keypoints =====
// Per kp: conv2/Theta needed only at the 4 clamped interp corners; conv1 only
// at their 4x4 h-neighborhood. Gather 6x6x64 xp patch -> LDS; conv1 MFMA
// (4x M=16, K=576) with Tab/BN/relu epilogue -> bf16 h patch in LDS; conv2
// MFMA (M=16 = 4kp x 4corners, K=1152) -> BN+relu per corner (the R18 bug:
// this relu was missing) -> interp weights -> th0.
__global__ __launch_bounds__(256, 2) void spconv_k(
    const short* __restrict__ XP, const short* __restrict__ B1,
    const short* __restrict__ B2, const float* __restrict__ Tab,
    const int* __restrict__ kp, float* __restrict__ th0g)
{
    __shared__ __align__(16) short xL[10368];      // 4kp x 36(pos) x 72(ch pad)
    __shared__ __align__(16) short hL[8768];       // 4kp x (16pos x 136 + 16 pad)
    __shared__ int   sPY[4], sPX[4], sCY[4][2], sCX[4][2], sB[4];
    __shared__ float sWT[4][4];
    const int bid = blockIdx.x;
    const int tid = threadIdx.x;
    const int wv = tid>>6, lane = tid&63;
    const int l15 = lane&15, lg = lane>>4;

    if (tid < 4){
        int m = bid*4 + tid;
        sB[tid] = m >> 9;
        float ix = (float)kp[m*2+0]/511.f*125.f;
        float iy = (float)kp[m*2+1]/511.f*125.f;
        float x0f = floorf(ix), y0f = floorf(iy);
        float wx = ix-x0f, wy = iy-y0f;
        int X0 = (int)x0f, Y0 = (int)y0f;
        bool vx1 = (x0f+1.f <= 125.f), vy1 = (y0f+1.f <= 125.f);
        int X1 = vx1 ? X0+1 : 125;
        int Y1 = vy1 ? Y0+1 : 125;
        int pX0 = min(X0,124), pY0 = min(Y0,124);
        sPX[tid]=pX0; sPY[tid]=pY0;
        sCX[tid][0]=X0-pX0; sCX[tid][1]=X1-pX0;
        sCY[tid][0]=Y0-pY0; sCY[tid][1]=Y1-pY0;
        sWT[tid][0] = (1.f-wx)*(1.f-wy);
        sWT[tid][1] = vx1 ? wx*(1.f-wy) : 0.f;
        sWT[tid][2] = vy1 ? (1.f-wx)*wy : 0.f;
        sWT[tid][3] = (vx1&&vy1) ? wx*wy : 0.f;
    }
    __syncthreads();

    // stage 4 xp patches (6x6 pos x 64ch) -> xL, ch padded to 72
    for (int e = tid; e < 1152; e += 256){
        int pair = e >> 3, seg = e & 7;
        int ki = pair/36, rem = pair - ki*36;
        int row = rem/6, col = rem - row*6;
        const short* src = XP + (((size_t)sB[ki]*130 + sPY[ki]+row)*130
                                 + sPX[ki]+col)*64 + seg*8;
        int4 v = *(const int4*)src;
        *(int4*)&xL[(ki*36 + rem)*72 + seg*8] = v;
    }
    __syncthreads();

    // ---- conv1: 4x (M=16 pos) x (N=32 co per wave via nt) ----
    f32x4 a1[4][2];
    #pragma unroll
    for (int i=0;i<4;i++){ a1[i][0]=(f32x4)(0.f); a1[i][1]=(f32x4)(0.f); }
    {
        const int py = l15>>2, px = l15&3;
        for (int cc=0; cc<2; ++cc){
            #pragma unroll
            for (int k9=0;k9<9;k9++){
                const int ky = k9/3, kx = k9 - (k9/3)*3;
                bf16x8 A[4], Bv[2];
                #pragma unroll
                for (int mt=0;mt<4;mt++)
                    A[mt] = *(const bf16x8*)&xL[(mt*36 + (py+ky)*6 + (px+kx))*72
                                                + cc*32 + lg*8];
                const int ko = k9*64 + cc*32;
                Bv[0] = *(const bf16x8*)(B1 + (wv*32 +     l15)*576 + ko + lg*8);
                Bv[1] = *(const bf16x8*)(B1 + (wv*32 + 16 + l15)*576 + ko + lg*8);
                #pragma unroll
                for (int mt=0;mt<4;mt++){
                    a1[mt][0] = __builtin_amdgcn_mfma_f32_16x16x32_bf16(A[mt], Bv[0], a1[mt][0],0,0,0);
                    a1[mt][1] = __builtin_amdgcn_mfma_f32_16x16x32_bf16(A[mt], Bv[1], a1[mt][1],0,0,0);
                }
            }
        }
    }
    // epilogue conv1 -> hL (bf16), Tab affine + BN + relu (matches dense conv1)
    #pragma unroll
    for (int mt=0;mt<4;mt++){
        const int pY0 = sPY[mt], pX0 = sPX[mt];
        #pragma unroll
        for (int reg=0;reg<4;reg++){
            const int p = lg*4 + reg;
            const int py = p>>2, px = p&3;
            const int hy = pY0+py, hx = pX0+px;
            const int pyb = (hy==0)?0:((hy==127)?2:1);
            const int pxb = (hx==0)?0:((hx==127)?2:1);
            #pragma unroll
            for (int nt=0;nt<2;nt++){
                const int co = wv*32 + nt*16 + l15;
                const float* t3 = Tab + ((size_t)(pyb*3+pxb)*128 + co)*3;
                float a = a1[mt][nt][reg];
                a += t3[0] + t3[1]*(float)hx + t3[2]*(float)hy;
                float v = fmaxf(a*BN_S, 0.f);
                hL[mt*2192 + p*136 + co] = (short)f2b(v);
            }
        }
    }
    __syncthreads();

    // ---- conv2: M=16 (4kp x 4 corners), wave wv -> co wv*32..+31 ----
    f32x4 a2[2];
    a2[0]=(f32x4)(0.f); a2[1]=(f32x4)(0.f);
    {
        const int ki = l15>>2, c = l15&3, cy = c>>1, cx = c&1;
        const int hbase = ki*2192 + (sCY[ki][cy]*4 + sCX[ki][cx])*136;
        for (int cc=0; cc<4; ++cc){
            #pragma unroll
            for (int k9=0;k9<9;k9++){
                const int ky = k9/3, kx = k9 - (k9/3)*3;
                bf16x8 A = *(const bf16x8*)&hL[hbase + (ky*4+kx)*136 + cc*32 + lg*8];
                const int ko = k9*128 + cc*32;
                bf16x8 Bv0 = *(const bf16x8*)(B2 + (wv*32 +     l15)*1152 + ko + lg*8);
                bf16x8 Bv1 = *(const bf16x8*)(B2 + (wv*32 + 16 + l15)*1152 + ko + lg*8);
                a2[0] = __builtin_amdgcn_mfma_f32_16x16x32_bf16(A, Bv0, a2[0],0,0,0);
                a2[1] = __builtin_amdgcn_mfma_f32_16x16x32_bf16(A, Bv1, a2[1],0,0,0);
            }
        }
    }
    // interp epilogue: Theta = relu(BN_S * conv2) per corner, THEN weight.
    // (R18 bug: the relu/BN was missing here.)
    {
        const float* w4 = sWT[lg];
        #pragma unroll
        for (int nt=0;nt<2;nt++){
            float c0 = fmaxf(a2[nt][0]*BN_S, 0.f);
            float c1 = fmaxf(a2[nt][1]*BN_S, 0.f);
            float c2 = fmaxf(a2[nt][2]*BN_S, 0.f);
            float c3 = fmaxf(a2[nt][3]*BN_S, 0.f);
            float r = ((c0*w4[0] + c1*w4[1]) + c2*w4[2]) + c3*w4[3];
            th0g[(size_t)(bid*4+lg)*128 + wv*32 + nt*16 + l15] = r;
        }
    }
}

// ===== constants: shuffle-based reduce (1 block, 1024 thr) =====
__global__ __launch_bounds__(1024) void consts_red_k(float* __restrict__ cbuf,
    float* __restrict__ pgn, float* __restrict__ ctrl)
{
    __shared__ float part[16][4];
    __shared__ float res[4];
    int g = threadIdx.x;
    int i = g >> 5, j = g & 31;
    float xs = (j + 0.5f)*(2.0f/32.0f) - 1.0f;
    float ys = (i + 0.5f)*(2.0f/32.0f) - 1.0f;
    float norm = (xs + 1.0f)*0.5f;
    float r_ = 1.0f + norm*31.0f;
    float r_s = (r_ - 1.0f)/31.0f*2.0f*32.0f/512.0f;
    float t_s = (ys + 1.0f)*3.14159265358979323846f;
    float bx = r_s*cosf(t_s);
    float by = r_s*sinf(t_s);

    float mnx=bx, mxx=bx, mny=by, mxy=by;
    #pragma unroll
    for (int s=1; s<64; s<<=1){
        mnx = fminf(mnx, __shfl_xor(mnx, s));
        mxx = fmaxf(mxx, __shfl_xor(mxx, s));
        mny = fminf(mny, __shfl_xor(mny, s));
        mxy = fmaxf(mxy, __shfl_xor(mxy, s));
    }
    int wv = g>>6, ln = g&63;
    if (ln == 0){ part[wv][0]=mnx; part[wv][1]=mxx; part[wv][2]=mny; part[wv][3]=mxy; }
    __syncthreads();
    if (g < 4){
        float v = part[0][g];
        for (int t=1;t<16;t++) v = (g&1) ? fmaxf(v, part[t][g]) : fminf(v, part[t][g]);
        res[g] = v;
    }
    __syncthreads();
    float minx=res[0], maxx=res[1], miny=res[2], maxy=res[3];
    float ptpx = maxx-minx, ptpy = maxy-miny;
    if (g == 0){ cbuf[0]=minx; cbuf[1]=miny; cbuf[2]=ptpx; cbuf[3]=ptpy; }

    float pgx = (bx - minx)/(ptpx + 1e-8f)*0.3f + 0.35f;
    float pgy = (by - miny)/(ptpy + 1e-8f)*0.3f + 0.35f;
    pgn[2*g]   = pgx;
    pgn[2*g+1] = pgy;
    if ((i&3)==0 && (j&3)==0){ int t = (i>>2)*8 + (j>>2); ctrl[t*2]=pgx; ctrl[t*2+1]=pgy; }
}

// ===== Ug fill: bf16 U+ matrix [1024 g][96 k] =====
__global__ __launch_bounds__(256) void ug_fill_k(const float* __restrict__ pgn,
    const float* __restrict__ ctrl, unsigned short* __restrict__ Ug)
{
    __shared__ float sc[64][2];
    int g = blockIdx.x*256 + threadIdx.x;
    for (int e = threadIdx.x; e < 128; e += 256) sc[e>>1][e&1] = ctrl[e];
    __syncthreads();
    float px = pgn[2*g], py = pgn[2*g+1];
    float gg2 = px*px + py*py;
    unsigned int* dst = (unsigned int*)(Ug + (size_t)g*96);
    #pragma unroll
    for (int t=0;t<64;t+=2){
        float cx0=sc[t][0],   cy0=sc[t][1];
        float cx1=sc[t+1][0], cy1=sc[t+1][1];
        float r20 = fmaxf(gg2 + (cx0*cx0+cy0*cy0) - 2.f*(px*cx0+py*cy0), 0.f);
        float r21 = fmaxf(gg2 + (cx1*cx1+cy1*cy1) - 2.f*(px*cx1+py*cy1), 0.f);
        float u0 = r20*logf(sqrtf(r20+1e-12f)+1e-6f);
        float u1 = r21*logf(sqrtf(r21+1e-12f)+1e-6f);
        dst[t>>1] = (unsigned)f2b(u0) | ((unsigned)f2b(u1)<<16);
    }
    dst[32] = (unsigned)f2b(1.f) | ((unsigned)f2b(px)<<16);
    dst[33] = (unsigned)f2b(py);               // hi half = 0
    #pragma unroll
    for (int t=34;t<48;t++) dst[t] = 0u;
}

// ===== fused MLP+TPS: lin1 -> lin2 -> lin3 -> tps GEMM (th0 precomputed) =====
__global__ __launch_bounds__(256) void mlp_tps_k(const float* __restrict__ th0g,
    const float* __restrict__ l1w, const float* __restrict__ l1b,
    const float* __restrict__ l2w, const float* __restrict__ l2b,
    const float* __restrict__ l3w, const float* __restrict__ l3b,
    const unsigned short* __restrict__ Ug, float* __restrict__ bxy)
{
    __shared__ float th0[8][128];
    __shared__ float th1[8][256];
    __shared__ float th2[8][256];
    __shared__ float sth[8][132];
    __shared__ __align__(16) unsigned short sW[16][96];
    const int m0 = blockIdx.x*8;
    const int tid = threadIdx.x;

    #pragma unroll
    for (int it=0; it<4; ++it){
        int e = tid + it*256;
        th0[e>>7][e&127] = th0g[(size_t)(m0 + (e>>7))*128 + (e&127)];
    }
    __syncthreads();
    // ---- lin1 ----
    {
        int o = tid;
        float acc[8] = {0,0,0,0,0,0,0,0};
        const float* wr = l1w + o*128;
        for (int i=0;i<128;i++){
            float wv = wr[i];
            #pragma unroll
            for (int j=0;j<8;j++) acc[j] += th0[j][i]*wv;
        }
        float bv = l1b[o];
        #pragma unroll
        for (int j=0;j<8;j++) th1[j][o] = fmaxf((acc[j]+bv)*BN_S, 0.f);
    }
    __syncthreads();
    // ---- lin2 ----
    {
        int o = tid;
        float acc[8] = {0,0,0,0,0,0,0,0};
        const float* wr = l2w + o*256;
        for (int i=0;i<256;i++){
            float wv = wr[i];
            #pragma unroll
            for (int j=0;j<8;j++) acc[j] += th1[j][i]*wv;
        }
        float bv = l2b[o];
        #pragma unroll
        for (int j=0;j<8;j++) th2[j][o] = fmaxf(acc[j]+bv, 0.f);
    }
    __syncthreads();
    // ---- lin3 (tanh -> theta) ----
    if (tid < NPAR){
        int o = tid;
        float acc[8] = {0,0,0,0,0,0,0,0};
        const float* wr = l3w + o*256;
        for (int i=0;i<256;i++){
            float wv = wr[i];
            #pragma unroll
            for (int j=0;j<8;j++) acc[j] += th2[j][i]*wv;
        }
        float bv = l3b[o];
        #pragma unroll
        for (int j=0;j<8;j++) sth[j][o] = tanhf(acc[j]+bv);
    }
    __syncthreads();
    // ---- W+ prep ----
    if (tid < 16){
        int kpi = tid>>1, c = tid&1;
        float s = 0.f;
        for (int p=0;p<63;p++){ float w = sth[kpi][2*p+c]; s += w; sW[tid][1+p] = f2b(w); }
        sW[tid][0]  = f2b(-s);
        sW[tid][64] = f2b(sth[kpi][126+c]);
        sW[tid][65] = f2b(sth[kpi][128+c]);
        sW[tid][66] = f2b(sth[kpi][130+c]);
        for (int p=67;p<96;p++) sW[tid][p] = 0;
    }
    __syncthreads();
    // ---- TPS MFMA: bxy = Ug(1024x96) @ W+(96x16cols) ----
    const int wv = tid>>6, lane = tid&63;
    const int l15 = lane&15, lg = lane>>4;
    bf16x8 Bf[3];
    #pragma unroll
    for (int ks=0;ks<3;ks++) Bf[ks] = *(const bf16x8*)&sW[l15][ks*32 + lg*8];
    const int gbase = wv*256;
    const int kpg = m0 + (l15>>1), c = l15&1;
    #pragma unroll
    for (int mf=0; mf<16; ++mf){
        f32x4 acc2 = (f32x4)(0.f);
        const unsigned short* ap = Ug + (size_t)(gbase + mf*16 + l15)*96 + lg*8;
        #pragma unroll
        for (int ks=0;ks<3;ks++){
            bf16x8 Af = *(const bf16x8*)(ap + ks*32);
            acc2 = __builtin_amdgcn_mfma_f32_16x16x32_bf16(Af, Bf[ks], acc2,0,0,0);
        }
        float* dst = bxy + ((size_t)kpg*2 + c)*1024 + gbase + mf*16 + lg*4;
        #pragma unroll
        for (int r=0;r<4;r++) dst[r] = acc2[r];
    }
}

// ===== sample: pure gather, one (keypoint, channel) per block ==============
__global__ __launch_bounds__(256) void sample3_k(const int* __restrict__ kp,
    const float* __restrict__ bxy, const float* __restrict__ pgn,
    const float* __restrict__ cbuf, const float* __restrict__ imgs,
    float* __restrict__ out)
{
    const int bid = blockIdx.x;
    const int m = ((bid & 7) << 8) | (bid >> 3);   // bijective: 2048 = 8*256
    const int ch = blockIdx.y;
    const int tid = threadIdx.x;
    const int b = m >> 9;
    const float vminx = cbuf[0] + ((float)kp[m*2+0]/512.f*2.f - 1.f);
    const float vminy = cbuf[1] + ((float)kp[m*2+1]/512.f*2.f - 1.f);
    const float ptpx = cbuf[2], ptpy = cbuf[3];
    const int g0 = tid*4;
    f32x4 zbx = *(const f32x4*)&bxy[((size_t)m*2+0)*1024 + g0];
    f32x4 zby = *(const f32x4*)&bxy[((size_t)m*2+1)*1024 + g0];
    f32x4 pga = *(const f32x4*)&pgn[2*g0];
    f32x4 pgb = *(const f32x4*)&pgn[2*g0+4];
    float px[4] = {pga[0], pga[2], pgb[0], pgb[2]};
    float py[4] = {pga[1], pga[3], pgb[1], pgb[3]};
    const float* ic = imgs + ((size_t)b*3 + ch)*HOImg*HOImg;
    f32x4 o;
    #pragma unroll
    for (int i=0;i<4;i++){
        float wnx = px[i] + zbx[i];
        float wny = py[i] + zby[i];
        float wxr = (wnx - 0.35f)/0.3f*ptpx + vminx;
        float wyr = (wny - 0.35f)/0.3f*ptpy + vminy;
        float ix = ((wxr + 1.f)*512.f - 1.f)*0.5f;
        float iy = ((wyr + 1.f)*512.f - 1.f)*0.5f;
        float x0f = floorf(ix), y0f = floorf(iy);
        float fx = ix-x0f, fy = iy-y0f;
        float w00=(1.f-fx)*(1.f-fy), w10=fx*(1.f-fy), w01=(1.f-fx)*fy, w11=fx*fy;
        bool vx0 = (x0f>=0.f)&&(x0f<=511.f), vx1 = (x0f+1.f>=0.f)&&(x0f+1.f<=511.f);
        bool vy0 = (y0f>=0.f)&&(y0f<=511.f), vy1 = (y0f+1.f>=0.f)&&(y0f+1.f<=511.f);
        float m00 = (vx0&&vy0)?w00:0.f;
        float m10 = (vx1&&vy0)?w10:0.f;
        float m01 = (vx0&&vy1)?w01:0.f;
        float m11 = (vx1&&vy1)?w11:0.f;
        int X0 = (int)fminf(fmaxf(x0f,0.f),511.f);
        int X1 = (int)fminf(fmaxf(x0f+1.f,0.f),511.f);
        int Y0 = (int)fminf(fmaxf(y0f,0.f),511.f);
        int Y1 = (int)fminf(fmaxf(y0f+1.f,0.f),511.f);
        int i00 = Y0*HOImg+X0, i10 = Y0*HOImg+X1, i01 = Y1*HOImg+X0, i11 = Y1*HOImg+X1;
        o[i] = ic[i00]*m00 + ic[i10]*m10 + ic[i01]*m01 + ic[i11]*m11;
    }
    *(f32x4*)&out[((size_t)(m*3+ch))*GG + g0] = o;
}

// ============================ launcher =======================================
extern "C" void kernel_launch(void* const* d_in, const int* in_sizes, int n_in,
                              void* d_out, int out_size, void* d_ws, size_t ws_size,
                              hipStream_t stream)
{
    const float* x    = (const float*)d_in[0];
    const float* imgs = (const float*)d_in[1];
    const int*   kp   = (const int*)d_in[2];
    const float* c1w  = (const float*)d_in[3];
    const float* c2w  = (const float*)d_in[4];
    const float* l1w  = (const float*)d_in[5];
    const float* l1b  = (const float*)d_in[6];
    const float* l2w  = (const float*)d_in[7];
    const float* l2b  = (const float*)d_in[8];
    const float* l3w  = (const float*)d_in[9];
    const float* l3b  = (const float*)d_in[10];
    float* out = (float*)d_out;

    // ---- workspace layout (alias-audited; nothing aliases) ----
    // [0, 8.66MB)     xp bf16 (written prep_xb, read spconv)
    // [32.51, 33.56)  th0g (written spconv, read mlp_tps)
    // [49.55, 50.07)  B1 (147KB), B2 (295KB)
    // [50.07, 67.07)  Ug, pgn, cbuf, ctrl, Tab, bxy — dedicated
    char* W = (char*)d_ws;
    short* xph   = (short*)(W + 0);
    constexpr size_t OFF_HH = 32514048;
    float* th0g = (float*)(W + OFF_HH);                // 1,048,576 B
    constexpr size_t OFF_B = OFF_HH + 17039360;        // 49,553,408
    short* B1 = (short*)(W + OFF_B);                   // 147,456
    short* B2 = (short*)(W + OFF_B + 221184);          // 294,912
    constexpr size_t OFF_C = OFF_B + 516096;           // 50,069,504
    unsigned short* Ug = (unsigned short*)(W + OFF_C);          // 196,608
    float* pgn  = (float*)(W + OFF_C + 196608);                 // 8,192
    float* cbuf = (float*)(W + OFF_C + 204800);                 // 256
    float* ctrl = (float*)(W + OFF_C + 205056);                 // 512
    float* Tab  = (float*)(W + OFF_C + 205568);                 // 13,824
    float* bxy  = (float*)(W + OFF_C + 219392);                 // 16,777,216

    hipLaunchKernelGGL(prep_xb_k, dim3(2,130,4), dim3(256), 0, stream, x, xph);
    hipLaunchKernelGGL(prep_misc_k, dim3(261), dim3(256), 0, stream,
                       c1w, c2w, B1, B2, Tab);
    hipLaunchKernelGGL(consts_red_k, dim3(1), dim3(1024), 0, stream, cbuf, pgn, ctrl);
    hipLaunchKernelGGL(ug_fill_k, dim3(4), dim3(256), 0, stream, pgn, ctrl, Ug);

    hipLaunchKernelGGL(spconv_k, dim3(MM/4), dim3(256), 0, stream,
                       xph, B1, B2, Tab, kp, th0g);

    hipLaunchKernelGGL(mlp_tps_k, dim3(MM/8), dim3(256), 0, stream,
                       th0g, l1w, l1b, l2w, l2b, l3w, l3b, Ug, bxy);
    hipLaunchKernelGGL(sample3_k, dim3(MM, 3), dim3(256), 0, stream,
                       kp, bxy, pgn, cbuf, imgs, out);
}